// Round 1
// baseline (917.181 us; speedup 1.0000x reference)
//
#include <hip/hip_runtime.h>

#define DEV __device__ __forceinline__

typedef __attribute__((ext_vector_type(8))) short short8;    // 8 bf16 (4 VGPRs)
typedef __attribute__((ext_vector_type(16))) float float16;  // MFMA 32x32 accumulator

// ---------- helpers ----------
DEV unsigned short f2bf(float x) {
    unsigned u = __float_as_uint(x);
    unsigned r = (u + 0x7FFFu + ((u >> 16) & 1u)) >> 16;
    return (unsigned short)r;
}
DEV float bf2f(unsigned short v) {
    return __uint_as_float(((unsigned)v) << 16);
}
DEV float fastcos(float x) {  // cos(x), x in radians
    float r = x * 0.15915494309189535f;  // -> revolutions
    r = r - floorf(r);                   // [0,1)
    return __builtin_amdgcn_cosf(r);     // v_cos_f32: cos(2*pi*r)
}

// ---------- K0: build transposed / fragment-packed weights ----------
__global__ void prep_kernel(const float* __restrict__ W_user, const float* __restrict__ W_item,
                            const float* __restrict__ We_ui, const float* __restrict__ be_ui,
                            const float* __restrict__ We_iu, const float* __restrict__ be_iu,
                            const float* __restrict__ dW1, const float* __restrict__ dW2,
                            float* __restrict__ Wt_user, float* __restrict__ Wt_item,
                            unsigned short* __restrict__ Wb, float* __restrict__ bc,
                            float* __restrict__ W1t, float* __restrict__ W2t) {
    int t = threadIdx.x;
    for (int i = t; i < 1024; i += 256) {           // W[k][d] -> Wt[d][k], 32x32
        int k = i / 32, d = i % 32;
        Wt_user[d * 32 + k] = W_user[i];
        Wt_item[d * 32 + k] = W_item[i];
    }
    for (int i = t; i < 4096; i += 256) {           // MFMA B fragments (bf16)
        int kt   = i >> 10;          // k-tile 0..3
        int rem  = i & 1023;
        int n2   = rem >> 9;         // col-tile 0..1
        int rem2 = rem & 511;
        int l    = rem2 >> 3;        // lane 0..63
        int ii   = rem2 & 7;         // elem 0..7
        int k = kt * 16 + (l >> 5) * 8 + ii;
        int n = (l & 31);
        float v = n2 ? We_iu[k * 32 + n] : We_ui[k * 32 + n];
        Wb[i] = f2bf(v);
    }
    for (int i = t; i < 64; i += 256)
        bc[i] = (i < 32) ? be_ui[i] : be_iu[i - 32];
    for (int i = t; i < 4096; i += 256) {           // dec_W1[k][j] -> W1t[j][k], 64x64
        int j = i / 64, k = i % 64;
        W1t[i] = dW1[k * 64 + j];
    }
    for (int i = t; i < 1024; i += 256) {           // dec_W2[j][c] -> W2t[c][j], 16x64
        int c = i / 64, j = i % 64;
        W2t[i] = dW2[j * 16 + c];
    }
}

// ---------- K1: h = mem[ids] @ W  (one thread per row) ----------
__global__ __launch_bounds__(256) void node_linear_kernel(
        const float* __restrict__ mem, const int* __restrict__ ids,
        const float* __restrict__ Wt, float* __restrict__ h, int B) {
    int r = blockIdx.x * 256 + threadIdx.x;
    if (r >= B) return;
    int id = ids[r];
    const float4* m4 = (const float4*)(mem + (size_t)id * 32);
    float m[32];
#pragma unroll
    for (int q = 0; q < 8; ++q) {
        float4 v = m4[q];
        m[4 * q + 0] = v.x; m[4 * q + 1] = v.y; m[4 * q + 2] = v.z; m[4 * q + 3] = v.w;
    }
    float* hr = h + (size_t)r * 32;
    for (int db = 0; db < 8; ++db) {   // 4 outputs per iter
        float acc[4];
#pragma unroll
        for (int u = 0; u < 4; ++u) {
            const float* wr = Wt + (size_t)(db * 4 + u) * 32;
            float a = 0.f;
#pragma unroll
            for (int k = 0; k < 32; ++k) a = fmaf(m[k], wr[k], a);
            acc[u] = a;
        }
        float4 o; o.x = acc[0]; o.y = acc[1]; o.z = acc[2]; o.w = acc[3];
        *(float4*)(hr + db * 4) = o;
    }
}

// ---------- K2: proj = feat @ [We_ui|We_iu] + bias, bf16 out — MFMA version ----------
__global__ __launch_bounds__(256) void proj_mfma_kernel(
        const float* __restrict__ feat, const unsigned short* __restrict__ Wb,
        const float* __restrict__ bc, unsigned short* __restrict__ proj, int NE) {
    __shared__ unsigned short lds[128 * 72];
    const int lane = threadIdx.x & 63;
    const int wave = threadIdx.x >> 6;
    const int col  = lane & 31;
    const int half = lane >> 5;

    short8 bfrag[8];
    const short8* wb8 = (const short8*)Wb;
#pragma unroll
    for (int f = 0; f < 8; ++f) bfrag[f] = wb8[f * 64 + lane];

    int r = blockIdx.x * 128 + wave * 32 + col;
    if (r >= NE) r = NE - 1;  // clamp; stores are guarded below
    const float* fr = feat + (size_t)r * 64 + half * 8;
    short8 afrag[4];
#pragma unroll
    for (int t = 0; t < 4; ++t) {
        float4 a = *(const float4*)(fr + t * 16);
        float4 b = *(const float4*)(fr + t * 16 + 4);
        short8 s;
        s[0] = (short)f2bf(a.x); s[1] = (short)f2bf(a.y);
        s[2] = (short)f2bf(a.z); s[3] = (short)f2bf(a.w);
        s[4] = (short)f2bf(b.x); s[5] = (short)f2bf(b.y);
        s[6] = (short)f2bf(b.z); s[7] = (short)f2bf(b.w);
        afrag[t] = s;
    }

    float16 acc0, acc1;
    float b0 = bc[col], b1 = bc[32 + col];
#pragma unroll
    for (int i = 0; i < 16; ++i) { acc0[i] = b0; acc1[i] = b1; }
#pragma unroll
    for (int t = 0; t < 4; ++t) {
        acc0 = __builtin_amdgcn_mfma_f32_32x32x16_bf16(afrag[t], bfrag[t * 2 + 0], acc0, 0, 0, 0);
        acc1 = __builtin_amdgcn_mfma_f32_32x32x16_bf16(afrag[t], bfrag[t * 2 + 1], acc1, 0, 0, 0);
    }

#pragma unroll
    for (int reg = 0; reg < 16; ++reg) {
        int rl = wave * 32 + (reg & 3) + 8 * (reg >> 2) + 4 * half;
        lds[rl * 72 + col]      = f2bf(acc0[reg]);
        lds[rl * 72 + 32 + col] = f2bf(acc1[reg]);
    }
    __syncthreads();

    int trow = threadIdx.x >> 1, thalf = threadIdx.x & 1;
    int grow = blockIdx.x * 128 + trow;
    if (grow < NE) {
        const uint4* lsrc = (const uint4*)(lds + trow * 72 + thalf * 32);
        uint4* gdst = (uint4*)(proj + (size_t)grow * 64 + thalf * 32);
#pragma unroll
        for (int s = 0; s < 4; ++s) gdst[s] = lsrc[s];
    }
}

// ---------- CSR build: histogram -> scan -> scatter ----------
// Node space: [0,B) = dst of ui edges (agg_item), [B,2B) = dst of iu edges (agg_user).
__global__ __launch_bounds__(256) void hist_kernel(
        const int* __restrict__ dst_ui, const int* __restrict__ dst_iu,
        int* __restrict__ cnt, int E, int B) {
    int ge = blockIdx.x * 256 + threadIdx.x;
    if (ge >= 2 * E) return;
    int d = (ge < E) ? dst_ui[ge] : (dst_iu[ge - E] + B);
    atomicAdd(cnt + d, 1);
}

// L1 scan: each block scans 1024 counts -> exclusive prefixes + block total
__global__ __launch_bounds__(256) void scan1_kernel(
        const int* __restrict__ cnt, int* __restrict__ base,
        int* __restrict__ part, int n) {
    __shared__ int sh[256];
    int t = threadIdx.x;
    int i0 = blockIdx.x * 1024 + t * 4;
    int c0 = (i0 + 0 < n) ? cnt[i0 + 0] : 0;
    int c1 = (i0 + 1 < n) ? cnt[i0 + 1] : 0;
    int c2 = (i0 + 2 < n) ? cnt[i0 + 2] : 0;
    int c3 = (i0 + 3 < n) ? cnt[i0 + 3] : 0;
    int s = c0 + c1 + c2 + c3;
    sh[t] = s; __syncthreads();
    for (int off = 1; off < 256; off <<= 1) {
        int v = sh[t];
        int a = (t >= off) ? sh[t - off] : 0;
        __syncthreads();
        sh[t] = v + a;
        __syncthreads();
    }
    int excl = sh[t] - s;
    if (t == 255) part[blockIdx.x] = sh[255];
    if (i0 + 0 < n) base[i0 + 0] = excl; excl += c0;
    if (i0 + 1 < n) base[i0 + 1] = excl; excl += c1;
    if (i0 + 2 < n) base[i0 + 2] = excl; excl += c2;
    if (i0 + 3 < n) base[i0 + 3] = excl;
}

// L2 scan: one block scans up to 4096 partials in place (exclusive)
__global__ __launch_bounds__(256) void scan2_kernel(int* __restrict__ part, int n) {
    __shared__ int sh[256];
    int t = threadIdx.x;
    int i0 = t * 16;
    int c[16];
#pragma unroll
    for (int q = 0; q < 16; ++q) c[q] = (i0 + q < n) ? part[i0 + q] : 0;
    int s = 0;
#pragma unroll
    for (int q = 0; q < 16; ++q) s += c[q];
    sh[t] = s; __syncthreads();
    for (int off = 1; off < 256; off <<= 1) {
        int v = sh[t];
        int a = (t >= off) ? sh[t - off] : 0;
        __syncthreads();
        sh[t] = v + a;
        __syncthreads();
    }
    int excl = sh[t] - s;
#pragma unroll
    for (int q = 0; q < 16; ++q) { if (i0 + q < n) part[i0 + q] = excl; excl += c[q]; }
}

// L3: add block offsets
__global__ __launch_bounds__(256) void scan3_kernel(
        int* __restrict__ base, const int* __restrict__ part, int n) {
    int i = blockIdx.x * 256 + threadIdx.x;
    if (i < n) base[i] += part[i >> 10];
}

// Scatter: pack (src, eidx, rt) into dst-sorted slots. atomicAdd mutates base[n]
// into the segment END pointer (start of n == base[n-1] afterwards).
__global__ __launch_bounds__(256) void scatter_kernel(
        const int* __restrict__ src_ui, const int* __restrict__ eidx_ui,
        const float* __restrict__ rt_ui, const int* __restrict__ dst_ui,
        const int* __restrict__ src_iu, const int* __restrict__ eidx_iu,
        const float* __restrict__ rt_iu, const int* __restrict__ dst_iu,
        int* __restrict__ base, int4* __restrict__ edata, int E, int B) {
    int ge = blockIdx.x * 256 + threadIdx.x;
    if (ge >= 2 * E) return;
    int s, ix, d; float tv;
    if (ge < E) {
        s = src_ui[ge]; ix = eidx_ui[ge]; tv = rt_ui[ge]; d = dst_ui[ge];
    } else {
        int e = ge - E;
        s = src_iu[e]; ix = eidx_iu[e]; tv = rt_iu[e]; d = dst_iu[e] + B;
    }
    int pos = atomicAdd(base + d, 1);
    edata[pos] = make_int4(s, ix, __float_as_int(tv), 0);
}

// ---------- K3': per-dst aggregation, 32 lanes per node, NO fp32 atomics ----------
__global__ __launch_bounds__(256) void agg_kernel(
        const int4* __restrict__ edata, const int* __restrict__ base,
        const float* __restrict__ h_user, const float* __restrict__ h_item,
        const unsigned short* __restrict__ proj,
        float* __restrict__ agg_user, float* __restrict__ agg_item,
        const float* __restrict__ tw, const float* __restrict__ tb, int B) {
    int g = threadIdx.x >> 5, d = threadIdx.x & 31;
    int n = blockIdx.x * 8 + g;
    if (n >= 2 * B) return;
    int type = (n >= B);
    int b1 = base[n];                      // post-scatter: end of segment n
    int b0 = n ? base[n - 1] : 0;          // end of segment n-1 == start of n
    const float* h = type ? h_item : h_user;
    const unsigned short* pr = proj + (type ? 32 : 0) + d;
    float twd = tw[d], tbd = tb[d];
    float acc = 0.f;
    if (b0 < b1) {
        int4 ed = edata[b0];
        for (int j = b0; j < b1; ++j) {
            int4 cur = ed;
            if (j + 1 < b1) ed = edata[j + 1];   // prefetch next tuple
            float pv = bf2f(pr[(size_t)cur.y * 64]);
            float c  = fastcos(fmaf(__int_as_float(cur.z), twd, tbd));
            acc += h[(size_t)cur.x * 32 + d] + pv + c;
        }
    }
    if (type) agg_user[(size_t)(n - B) * 32 + d] = acc;
    else      agg_item[(size_t)n * 32 + d] = acc;
}

// ---------- K4: relu + decoder MLP (one thread per row) ----------
__global__ __launch_bounds__(256) void decoder_kernel(
        const float* __restrict__ h_user, const float* __restrict__ h_item,
        const float* __restrict__ agg_user, const float* __restrict__ agg_item,
        const float* __restrict__ W1t, const float* __restrict__ b1,
        const float* __restrict__ W2t, const float* __restrict__ b2,
        const float* __restrict__ W3, const float* __restrict__ b3,
        float* __restrict__ out, int B) {
    int i = blockIdx.x * 256 + threadIdx.x;
    if (i >= B) return;
    float z[64];
    {
        const float4* a4 = (const float4*)(h_user + (size_t)i * 32);
        const float4* b4 = (const float4*)(agg_user + (size_t)i * 32);
#pragma unroll
        for (int q = 0; q < 8; ++q) {
            float4 a = a4[q], b = b4[q];
            z[4 * q + 0] = fmaxf(a.x + b.x, 0.f);
            z[4 * q + 1] = fmaxf(a.y + b.y, 0.f);
            z[4 * q + 2] = fmaxf(a.z + b.z, 0.f);
            z[4 * q + 3] = fmaxf(a.w + b.w, 0.f);
        }
    }
    {
        const float4* a4 = (const float4*)(h_item + (size_t)i * 32);
        const float4* b4 = (const float4*)(agg_item + (size_t)i * 32);
#pragma unroll
        for (int q = 0; q < 8; ++q) {
            float4 a = a4[q], b = b4[q];
            z[32 + 4 * q + 0] = fmaxf(a.x + b.x, 0.f);
            z[32 + 4 * q + 1] = fmaxf(a.y + b.y, 0.f);
            z[32 + 4 * q + 2] = fmaxf(a.z + b.z, 0.f);
            z[32 + 4 * q + 3] = fmaxf(a.w + b.w, 0.f);
        }
    }
    float x2[16];
#pragma unroll
    for (int c = 0; c < 16; ++c) x2[c] = b2[c];
    for (int jb = 0; jb < 8; ++jb) {
        float a[8];
#pragma unroll
        for (int u = 0; u < 8; ++u) {
            int j = jb * 8 + u;
            const float* wr = W1t + (size_t)j * 64;
            float acc = b1[j];
#pragma unroll
            for (int k = 0; k < 64; ++k) acc = fmaf(z[k], wr[k], acc);
            a[u] = fmaxf(acc, 0.f);
        }
#pragma unroll
        for (int c = 0; c < 16; ++c) {
            const float* w2r = W2t + (size_t)c * 64 + jb * 8;
            float acc = x2[c];
#pragma unroll
            for (int u = 0; u < 8; ++u) acc = fmaf(a[u], w2r[u], acc);
            x2[c] = acc;
        }
    }
    float o = b3[0];
#pragma unroll
    for (int c = 0; c < 16; ++c) o = fmaf(fmaxf(x2[c], 0.f), W3[c], o);
    out[i] = o;
}

extern "C" void kernel_launch(void* const* d_in, const int* in_sizes, int n_in,
                              void* d_out, int out_size, void* d_ws, size_t ws_size,
                              hipStream_t stream) {
    const float* mem_user = (const float*)d_in[0];
    const float* mem_item = (const float*)d_in[1];
    const int*   ids_user = (const int*)d_in[2];
    const int*   ids_item = (const int*)d_in[3];
    const int*   src_ui   = (const int*)d_in[4];
    const int*   dst_ui   = (const int*)d_in[5];
    const int*   src_iu   = (const int*)d_in[6];
    const int*   dst_iu   = (const int*)d_in[7];
    const int*   eidx_ui  = (const int*)d_in[8];
    const int*   eidx_iu  = (const int*)d_in[9];
    const float* rt_ui    = (const float*)d_in[10];
    const float* rt_iu    = (const float*)d_in[11];
    const float* feat     = (const float*)d_in[12];
    const float* W_user   = (const float*)d_in[13];
    const float* W_item   = (const float*)d_in[14];
    const float* We_ui    = (const float*)d_in[15];
    const float* be_ui    = (const float*)d_in[16];
    const float* We_iu    = (const float*)d_in[17];
    const float* be_iu    = (const float*)d_in[18];
    const float* tw       = (const float*)d_in[19];
    const float* tb       = (const float*)d_in[20];
    const float* dW1      = (const float*)d_in[21];
    const float* db1      = (const float*)d_in[22];
    const float* dW2      = (const float*)d_in[23];
    const float* db2      = (const float*)d_in[24];
    const float* dW3      = (const float*)d_in[25];
    const float* db3      = (const float*)d_in[26];

    const int B  = in_sizes[2];
    const int E  = in_sizes[4];
    const int NE = in_sizes[12] / 64;
    const int NB2 = 2 * B;

    float* w = (float*)d_ws;
    const size_t hsz = (size_t)B * 32;
    float* h_user   = w;
    float* h_item   = h_user + hsz;
    float* agg_user = h_item + hsz;
    float* agg_item = agg_user + hsz;
    float* Wt_user  = agg_item + hsz;
    float* Wt_item  = Wt_user + 1024;
    unsigned short* Wb = (unsigned short*)(Wt_item + 1024);  // 4096 bf16 = 2048 floats
    float* bc       = (float*)(Wb + 4096);
    float* W1t      = bc + 64;
    float* W2t      = W1t + 4096;
    unsigned short* proj = (unsigned short*)(W2t + 1024);    // [NE][64] bf16
    int* cnt  = (int*)(proj + (size_t)NE * 64);              // [2B]
    int* base = cnt + NB2;                                   // [2B]
    int* part = base + NB2;                                  // [4096]
    int4* edata = (int4*)(part + 4096);                      // [2E] x 16B (16B-aligned)

    prep_kernel<<<1, 256, 0, stream>>>(W_user, W_item, We_ui, be_ui, We_iu, be_iu, dW1, dW2,
                                       Wt_user, Wt_item, Wb, bc, W1t, W2t);
    hipMemsetAsync(cnt, 0, (size_t)NB2 * sizeof(int), stream);
    node_linear_kernel<<<(B + 255) / 256, 256, 0, stream>>>(mem_user, ids_user, Wt_user, h_user, B);
    node_linear_kernel<<<(B + 255) / 256, 256, 0, stream>>>(mem_item, ids_item, Wt_item, h_item, B);
    proj_mfma_kernel<<<(NE + 127) / 128, 256, 0, stream>>>(feat, Wb, bc, proj, NE);

    // CSR build over both edge types (global edge id in [0, 2E))
    int e2blocks = (2 * E + 255) / 256;
    hist_kernel<<<e2blocks, 256, 0, stream>>>(dst_ui, dst_iu, cnt, E, B);
    int nblk1 = (NB2 + 1023) / 1024;
    scan1_kernel<<<nblk1, 256, 0, stream>>>(cnt, base, part, NB2);
    scan2_kernel<<<1, 256, 0, stream>>>(part, nblk1);
    scan3_kernel<<<(NB2 + 255) / 256, 256, 0, stream>>>(base, part, NB2);
    scatter_kernel<<<e2blocks, 256, 0, stream>>>(src_ui, eidx_ui, rt_ui, dst_ui,
                                                 src_iu, eidx_iu, rt_iu, dst_iu,
                                                 base, edata, E, B);
    // Aggregate: one 32-lane group per node, plain stores (replaces 128M f32 atomics
    // and the agg memset — every node's agg row is written unconditionally)
    agg_kernel<<<(NB2 + 7) / 8, 256, 0, stream>>>(edata, base, h_user, h_item, proj,
                                                  agg_user, agg_item, tw, tb, B);
    decoder_kernel<<<(B + 255) / 256, 256, 0, stream>>>(h_user, h_item, agg_user, agg_item,
                                                        W1t, db1, W2t, db2, dW3, db3,
                                                        (float*)d_out, B);
}

// Round 2
// 815.245 us; speedup vs baseline: 1.1250x; 1.1250x over previous
//
#include <hip/hip_runtime.h>

#define DEV __device__ __forceinline__

typedef __attribute__((ext_vector_type(8))) short short8;    // 8 bf16 (4 VGPRs)
typedef __attribute__((ext_vector_type(16))) float float16;  // MFMA 32x32 accumulator

// ---------- helpers ----------
DEV unsigned short f2bf(float x) {
    unsigned u = __float_as_uint(x);
    unsigned r = (u + 0x7FFFu + ((u >> 16) & 1u)) >> 16;
    return (unsigned short)r;
}
DEV float bf2f(unsigned short v) {
    return __uint_as_float(((unsigned)v) << 16);
}
DEV float fastcos(float x) {  // cos(x), x in radians
    float r = x * 0.15915494309189535f;  // -> revolutions
    r = r - floorf(r);                   // [0,1)
    return __builtin_amdgcn_cosf(r);     // v_cos_f32: cos(2*pi*r)
}

// ---------- K0: build transposed / fragment-packed weights ----------
__global__ void prep_kernel(const float* __restrict__ W_user, const float* __restrict__ W_item,
                            const float* __restrict__ We_ui, const float* __restrict__ be_ui,
                            const float* __restrict__ We_iu, const float* __restrict__ be_iu,
                            const float* __restrict__ dW1, const float* __restrict__ dW2,
                            float* __restrict__ Wt_user, float* __restrict__ Wt_item,
                            unsigned short* __restrict__ Wb, float* __restrict__ bc,
                            float* __restrict__ W1t, float* __restrict__ W2t) {
    int t = threadIdx.x;
    for (int i = t; i < 1024; i += 256) {           // W[k][d] -> Wt[d][k], 32x32
        int k = i / 32, d = i % 32;
        Wt_user[d * 32 + k] = W_user[i];
        Wt_item[d * 32 + k] = W_item[i];
    }
    for (int i = t; i < 4096; i += 256) {           // MFMA B fragments (bf16)
        int kt   = i >> 10;          // k-tile 0..3
        int rem  = i & 1023;
        int n2   = rem >> 9;         // col-tile 0..1
        int rem2 = rem & 511;
        int l    = rem2 >> 3;        // lane 0..63
        int ii   = rem2 & 7;         // elem 0..7
        int k = kt * 16 + (l >> 5) * 8 + ii;
        int n = (l & 31);
        float v = n2 ? We_iu[k * 32 + n] : We_ui[k * 32 + n];
        Wb[i] = f2bf(v);
    }
    for (int i = t; i < 64; i += 256)
        bc[i] = (i < 32) ? be_ui[i] : be_iu[i - 32];
    for (int i = t; i < 4096; i += 256) {           // dec_W1[k][j] -> W1t[j][k], 64x64
        int j = i / 64, k = i % 64;
        W1t[i] = dW1[k * 64 + j];
    }
    for (int i = t; i < 1024; i += 256) {           // dec_W2[j][c] -> W2t[c][j], 16x64
        int c = i / 64, j = i % 64;
        W2t[i] = dW2[j * 16 + c];
    }
}

// ---------- K1: h = mem[ids] @ W  (one thread per row) ----------
__global__ __launch_bounds__(256) void node_linear_kernel(
        const float* __restrict__ mem, const int* __restrict__ ids,
        const float* __restrict__ Wt, float* __restrict__ h, int B) {
    int r = blockIdx.x * 256 + threadIdx.x;
    if (r >= B) return;
    int id = ids[r];
    const float4* m4 = (const float4*)(mem + (size_t)id * 32);
    float m[32];
#pragma unroll
    for (int q = 0; q < 8; ++q) {
        float4 v = m4[q];
        m[4 * q + 0] = v.x; m[4 * q + 1] = v.y; m[4 * q + 2] = v.z; m[4 * q + 3] = v.w;
    }
    float* hr = h + (size_t)r * 32;
    for (int db = 0; db < 8; ++db) {   // 4 outputs per iter
        float acc[4];
#pragma unroll
        for (int u = 0; u < 4; ++u) {
            const float* wr = Wt + (size_t)(db * 4 + u) * 32;
            float a = 0.f;
#pragma unroll
            for (int k = 0; k < 32; ++k) a = fmaf(m[k], wr[k], a);
            acc[u] = a;
        }
        float4 o; o.x = acc[0]; o.y = acc[1]; o.z = acc[2]; o.w = acc[3];
        *(float4*)(hr + db * 4) = o;
    }
}

// ---------- K2: proj = feat @ [We_ui|We_iu] + bias, bf16 out — MFMA version ----------
__global__ __launch_bounds__(256) void proj_mfma_kernel(
        const float* __restrict__ feat, const unsigned short* __restrict__ Wb,
        const float* __restrict__ bc, unsigned short* __restrict__ proj, int NE) {
    __shared__ unsigned short lds[128 * 72];
    const int lane = threadIdx.x & 63;
    const int wave = threadIdx.x >> 6;
    const int col  = lane & 31;
    const int half = lane >> 5;

    short8 bfrag[8];
    const short8* wb8 = (const short8*)Wb;
#pragma unroll
    for (int f = 0; f < 8; ++f) bfrag[f] = wb8[f * 64 + lane];

    int r = blockIdx.x * 128 + wave * 32 + col;
    if (r >= NE) r = NE - 1;  // clamp; stores are guarded below
    const float* fr = feat + (size_t)r * 64 + half * 8;
    short8 afrag[4];
#pragma unroll
    for (int t = 0; t < 4; ++t) {
        float4 a = *(const float4*)(fr + t * 16);
        float4 b = *(const float4*)(fr + t * 16 + 4);
        short8 s;
        s[0] = (short)f2bf(a.x); s[1] = (short)f2bf(a.y);
        s[2] = (short)f2bf(a.z); s[3] = (short)f2bf(a.w);
        s[4] = (short)f2bf(b.x); s[5] = (short)f2bf(b.y);
        s[6] = (short)f2bf(b.z); s[7] = (short)f2bf(b.w);
        afrag[t] = s;
    }

    float16 acc0, acc1;
    float b0 = bc[col], b1 = bc[32 + col];
#pragma unroll
    for (int i = 0; i < 16; ++i) { acc0[i] = b0; acc1[i] = b1; }
#pragma unroll
    for (int t = 0; t < 4; ++t) {
        acc0 = __builtin_amdgcn_mfma_f32_32x32x16_bf16(afrag[t], bfrag[t * 2 + 0], acc0, 0, 0, 0);
        acc1 = __builtin_amdgcn_mfma_f32_32x32x16_bf16(afrag[t], bfrag[t * 2 + 1], acc1, 0, 0, 0);
    }

#pragma unroll
    for (int reg = 0; reg < 16; ++reg) {
        int rl = wave * 32 + (reg & 3) + 8 * (reg >> 2) + 4 * half;
        lds[rl * 72 + col]      = f2bf(acc0[reg]);
        lds[rl * 72 + 32 + col] = f2bf(acc1[reg]);
    }
    __syncthreads();

    int trow = threadIdx.x >> 1, thalf = threadIdx.x & 1;
    int grow = blockIdx.x * 128 + trow;
    if (grow < NE) {
        const uint4* lsrc = (const uint4*)(lds + trow * 72 + thalf * 32);
        uint4* gdst = (uint4*)(proj + (size_t)grow * 64 + thalf * 32);
#pragma unroll
        for (int s = 0; s < 4; ++s) gdst[s] = lsrc[s];
    }
}

// ---------- K3a: build per-dst intrusive linked lists ----------
// Node space: [0,B) = dst of ui edges (agg_item), [B,2B) = dst of iu edges (agg_user).
// edata[ge] = {src, eidx, rel_time, next} written COALESCED; only the 4B
// atomicExch on head[] is a random access (replaces hist+scan+scatter's
// 2M random atomics + 134 MB of random 16B tuple stores).
__global__ __launch_bounds__(256) void link_kernel(
        const int* __restrict__ src_ui, const int* __restrict__ dst_ui,
        const int* __restrict__ eidx_ui, const float* __restrict__ rt_ui,
        const int* __restrict__ src_iu, const int* __restrict__ dst_iu,
        const int* __restrict__ eidx_iu, const float* __restrict__ rt_iu,
        int* __restrict__ head, int4* __restrict__ edata, int E, int B) {
    int ge = blockIdx.x * 256 + threadIdx.x;
    if (ge >= 2 * E) return;
    int s, ix, d; float tv;
    if (ge < E) {
        s = src_ui[ge]; ix = eidx_ui[ge]; tv = rt_ui[ge]; d = dst_ui[ge];
    } else {
        int e = ge - E;
        s = src_iu[e]; ix = eidx_iu[e]; tv = rt_iu[e]; d = dst_iu[e] + B;
    }
    int nxt = atomicExch(head + d, ge);
    edata[ge] = make_int4(s, ix, __float_as_int(tv), nxt);
}

// ---------- K3b: per-dst aggregation via chain walk, 32 lanes per node ----------
// Avg degree ~4; 524k independent groups hide the dependent-load latency.
// Per edge: ONE broadcast 16B tuple load (includes next ptr) + coalesced
// 128B h-row gather + 64B proj-row gather. Plain stores, zero fp32 atomics.
__global__ __launch_bounds__(256) void agg_kernel(
        const int4* __restrict__ edata, const int* __restrict__ head,
        const float* __restrict__ h_user, const float* __restrict__ h_item,
        const unsigned short* __restrict__ proj,
        float* __restrict__ agg_user, float* __restrict__ agg_item,
        const float* __restrict__ tw, const float* __restrict__ tb, int B) {
    int g = threadIdx.x >> 5, d = threadIdx.x & 31;
    int n = blockIdx.x * 8 + g;
    if (n >= 2 * B) return;
    int type = (n >= B);
    const float* h = type ? h_item : h_user;
    const unsigned short* pr = proj + (type ? 32 : 0) + d;
    float twd = tw[d], tbd = tb[d];
    float acc = 0.f;
    int e = head[n];
    while (e >= 0) {
        int4 cur = edata[e];
        float pv = bf2f(pr[(size_t)cur.y * 64]);
        float c  = fastcos(fmaf(__int_as_float(cur.z), twd, tbd));
        acc += h[(size_t)cur.x * 32 + d] + pv + c;
        e = cur.w;
    }
    if (type) agg_user[(size_t)(n - B) * 32 + d] = acc;
    else      agg_item[(size_t)n * 32 + d] = acc;
}

// ---------- K4: relu + decoder MLP (one thread per row) ----------
__global__ __launch_bounds__(256) void decoder_kernel(
        const float* __restrict__ h_user, const float* __restrict__ h_item,
        const float* __restrict__ agg_user, const float* __restrict__ agg_item,
        const float* __restrict__ W1t, const float* __restrict__ b1,
        const float* __restrict__ W2t, const float* __restrict__ b2,
        const float* __restrict__ W3, const float* __restrict__ b3,
        float* __restrict__ out, int B) {
    int i = blockIdx.x * 256 + threadIdx.x;
    if (i >= B) return;
    float z[64];
    {
        const float4* a4 = (const float4*)(h_user + (size_t)i * 32);
        const float4* b4 = (const float4*)(agg_user + (size_t)i * 32);
#pragma unroll
        for (int q = 0; q < 8; ++q) {
            float4 a = a4[q], b = b4[q];
            z[4 * q + 0] = fmaxf(a.x + b.x, 0.f);
            z[4 * q + 1] = fmaxf(a.y + b.y, 0.f);
            z[4 * q + 2] = fmaxf(a.z + b.z, 0.f);
            z[4 * q + 3] = fmaxf(a.w + b.w, 0.f);
        }
    }
    {
        const float4* a4 = (const float4*)(h_item + (size_t)i * 32);
        const float4* b4 = (const float4*)(agg_item + (size_t)i * 32);
#pragma unroll
        for (int q = 0; q < 8; ++q) {
            float4 a = a4[q], b = b4[q];
            z[32 + 4 * q + 0] = fmaxf(a.x + b.x, 0.f);
            z[32 + 4 * q + 1] = fmaxf(a.y + b.y, 0.f);
            z[32 + 4 * q + 2] = fmaxf(a.z + b.z, 0.f);
            z[32 + 4 * q + 3] = fmaxf(a.w + b.w, 0.f);
        }
    }
    float x2[16];
#pragma unroll
    for (int c = 0; c < 16; ++c) x2[c] = b2[c];
    for (int jb = 0; jb < 8; ++jb) {
        float a[8];
#pragma unroll
        for (int u = 0; u < 8; ++u) {
            int j = jb * 8 + u;
            const float* wr = W1t + (size_t)j * 64;
            float acc = b1[j];
#pragma unroll
            for (int k = 0; k < 64; ++k) acc = fmaf(z[k], wr[k], acc);
            a[u] = fmaxf(acc, 0.f);
        }
#pragma unroll
        for (int c = 0; c < 16; ++c) {
            const float* w2r = W2t + (size_t)c * 64 + jb * 8;
            float acc = x2[c];
#pragma unroll
            for (int u = 0; u < 8; ++u) acc = fmaf(a[u], w2r[u], acc);
            x2[c] = acc;
        }
    }
    float o = b3[0];
#pragma unroll
    for (int c = 0; c < 16; ++c) o = fmaf(fmaxf(x2[c], 0.f), W3[c], o);
    out[i] = o;
}

extern "C" void kernel_launch(void* const* d_in, const int* in_sizes, int n_in,
                              void* d_out, int out_size, void* d_ws, size_t ws_size,
                              hipStream_t stream) {
    const float* mem_user = (const float*)d_in[0];
    const float* mem_item = (const float*)d_in[1];
    const int*   ids_user = (const int*)d_in[2];
    const int*   ids_item = (const int*)d_in[3];
    const int*   src_ui   = (const int*)d_in[4];
    const int*   dst_ui   = (const int*)d_in[5];
    const int*   src_iu   = (const int*)d_in[6];
    const int*   dst_iu   = (const int*)d_in[7];
    const int*   eidx_ui  = (const int*)d_in[8];
    const int*   eidx_iu  = (const int*)d_in[9];
    const float* rt_ui    = (const float*)d_in[10];
    const float* rt_iu    = (const float*)d_in[11];
    const float* feat     = (const float*)d_in[12];
    const float* W_user   = (const float*)d_in[13];
    const float* W_item   = (const float*)d_in[14];
    const float* We_ui    = (const float*)d_in[15];
    const float* be_ui    = (const float*)d_in[16];
    const float* We_iu    = (const float*)d_in[17];
    const float* be_iu    = (const float*)d_in[18];
    const float* tw       = (const float*)d_in[19];
    const float* tb       = (const float*)d_in[20];
    const float* dW1      = (const float*)d_in[21];
    const float* db1      = (const float*)d_in[22];
    const float* dW2      = (const float*)d_in[23];
    const float* db2      = (const float*)d_in[24];
    const float* dW3      = (const float*)d_in[25];
    const float* db3      = (const float*)d_in[26];

    const int B  = in_sizes[2];
    const int E  = in_sizes[4];
    const int NE = in_sizes[12] / 64;
    const int NB2 = 2 * B;

    float* w = (float*)d_ws;
    const size_t hsz = (size_t)B * 32;
    float* h_user   = w;
    float* h_item   = h_user + hsz;
    float* agg_user = h_item + hsz;
    float* agg_item = agg_user + hsz;
    float* Wt_user  = agg_item + hsz;
    float* Wt_item  = Wt_user + 1024;
    unsigned short* Wb = (unsigned short*)(Wt_item + 1024);  // 4096 bf16 = 2048 floats
    float* bc       = (float*)(Wb + 4096);
    float* W1t      = bc + 64;
    float* W2t      = W1t + 4096;
    unsigned short* proj = (unsigned short*)(W2t + 1024);    // [NE][64] bf16
    int* head = (int*)(proj + (size_t)NE * 64);              // [2B]
    int4* edata = (int4*)(head + NB2);                       // [2E] x 16B (16B-aligned)

    prep_kernel<<<1, 256, 0, stream>>>(W_user, W_item, We_ui, be_ui, We_iu, be_iu, dW1, dW2,
                                       Wt_user, Wt_item, Wb, bc, W1t, W2t);
    hipMemsetAsync(head, 0xFF, (size_t)NB2 * sizeof(int), stream);   // head = -1

    // Order chosen for L3 warmth at agg time: proj's 192 MB streams first,
    // then h (67 MB) and edata (33.5 MB) are the most recently written data.
    proj_mfma_kernel<<<(NE + 127) / 128, 256, 0, stream>>>(feat, Wb, bc, proj, NE);
    node_linear_kernel<<<(B + 255) / 256, 256, 0, stream>>>(mem_user, ids_user, Wt_user, h_user, B);
    node_linear_kernel<<<(B + 255) / 256, 256, 0, stream>>>(mem_item, ids_item, Wt_item, h_item, B);

    int e2blocks = (2 * E + 255) / 256;
    link_kernel<<<e2blocks, 256, 0, stream>>>(src_ui, dst_ui, eidx_ui, rt_ui,
                                              src_iu, dst_iu, eidx_iu, rt_iu,
                                              head, edata, E, B);
    agg_kernel<<<(NB2 + 7) / 8, 256, 0, stream>>>(edata, head, h_user, h_item, proj,
                                                  agg_user, agg_item, tw, tb, B);
    decoder_kernel<<<(B + 255) / 256, 256, 0, stream>>>(h_user, h_item, agg_user, agg_item,
                                                        W1t, db1, W2t, db2, dW3, db3,
                                                        (float*)d_out, B);
}